// Round 2
// baseline (486.765 us; speedup 1.0000x reference)
//
#include <hip/hip_runtime.h>

// Slot_Merger_Cosine_avg — B=131072, S=9, D=64, fp32.
// out = [final_slots: B*S*D floats][slot_mask: B*S floats]
//
// Layout: 1 wave = 4 batches; 16 lanes per batch; each lane owns a float4
// chunk (4 of the 64 dims). Dots via 4-step shfl_xor butterfly in the
// 16-lane group. Memory-bound target: 609 MB @ ~6.3 TB/s => ~97 us.

constexpr int S = 9;
constexpr int D = 64;
#define EPS 1e-8f
#define SIM_THRESH 0.9f

__global__ __launch_bounds__(256) void slot_merge_kernel(
    const float* __restrict__ slots, float* __restrict__ out, int B) {
  const int tid  = blockIdx.x * 256 + threadIdx.x;
  const int lane = threadIdx.x & 63;
  const int wave = tid >> 6;       // global wave id
  const int q    = lane >> 4;      // sub-batch within wave (0..3)
  const int r    = lane & 15;      // float4 chunk index (0..15)
  const size_t b = (size_t)wave * 4 + q;
  if (b >= (size_t)B) return;

  // ---- load 9 float4 chunks (16B/lane, contiguous per 16-lane group) ----
  const float4* sp = (const float4*)(slots + b * (size_t)(S * D));
  float4 s[S];
#pragma unroll
  for (int i = 0; i < S; ++i) s[i] = sp[i * 16 + r];

  // ---- norms: n2[i] = |s_i|^2 reduced over the 16-lane group ----
  float n2[S], nrm[S];
#pragma unroll
  for (int i = 0; i < S; ++i) {
    float p = s[i].x * s[i].x + s[i].y * s[i].y + s[i].z * s[i].z + s[i].w * s[i].w;
    p += __shfl_xor(p, 1);
    p += __shfl_xor(p, 2);
    p += __shfl_xor(p, 4);
    p += __shfl_xor(p, 8);
    n2[i]  = p;
    nrm[i] = sqrtf(p);
  }

  // ---- merge mask rows as 9-bit masks (symmetric; diag from n2) ----
  // sim > T  <=>  g > T * (nrm_i*nrm_j + EPS)   (denominator always > 0)
  unsigned rm[S];
#pragma unroll
  for (int i = 0; i < S; ++i) {
    float denom = fmaf(nrm[i], nrm[i], EPS);
    rm[i] = (n2[i] > SIM_THRESH * denom) ? (1u << i) : 0u;
  }
#pragma unroll
  for (int i = 0; i < S; ++i) {
#pragma unroll
    for (int j = i + 1; j < S; ++j) {
      float p = s[i].x * s[j].x + s[i].y * s[j].y + s[i].z * s[j].z + s[i].w * s[j].w;
      p += __shfl_xor(p, 1);
      p += __shfl_xor(p, 2);
      p += __shfl_xor(p, 4);
      p += __shfl_xor(p, 8);
      float denom = fmaf(nrm[i], nrm[j], EPS);
      bool m = p > SIM_THRESH * denom;
      rm[i] |= m ? (1u << j) : 0u;
      rm[j] |= m ? (1u << i) : 0u;
    }
  }

  // ---- nums, killed, fast-path vote ----
  int nums[S];
  unsigned killed = 0;
  bool simple = true;
#pragma unroll
  for (int i = 0; i < S; ++i) {
    nums[i] = __popc(rm[i]);
    bool multi = nums[i] > 1;
    simple &= !multi;
    unsigned first = rm[i] & (unsigned)(-(int)rm[i]);  // lowest set bit
    killed |= multi ? (rm[i] ^ first) : 0u;            // row minus its first idx
  }

  float4* op = (float4*)(out + b * (size_t)(S * D));
  float*  mp = out + (size_t)B * (S * D) + b * (size_t)S;

  if (__all(simple)) {
    // nums[i] <= 1 for every row of all 4 batches in this wave:
    // writes are the identity, last_writer[j] = j, writer_vals = slots,
    // killed = 0  =>  final_slots = slots (bit-exact), slot_mask = 1.
#pragma unroll
    for (int j = 0; j < S; ++j) op[j * 16 + r] = s[j];
    if (r < S) mp[r] = 1.0f;
    return;
  }

  // ---- general path (statistically never taken; fully static indexing) ----
  float4 outv[S];
#pragma unroll
  for (int j = 0; j < S; ++j) outv[j] = s[j];   // fallback init (diag writer)

#pragma unroll
  for (int i = 0; i < S; ++i) {                 // sequential scatter, i ascending
    bool multi = nums[i] > 1;
    float4 wv = s[i];
    if (multi) {                                // masked average (new_slots row i)
      float ax = 0.f, ay = 0.f, az = 0.f, aw = 0.f;
#pragma unroll
      for (int k = 0; k < S; ++k) {
        float f = ((rm[i] >> k) & 1u) ? 1.0f : 0.0f;
        ax += f * s[k].x; ay += f * s[k].y; az += f * s[k].z; aw += f * s[k].w;
      }
      float den = (float)nums[i] + EPS;
      wv.x = ax / den; wv.y = ay / den; wv.z = az / den; wv.w = aw / den;
    }
    unsigned m = multi ? rm[i] : (1u << i);     // writes row i
#pragma unroll
    for (int j = 0; j < S; ++j) {
      if ((m >> j) & 1u) outv[j] = wv;          // last-writer-wins
    }
  }

#pragma unroll
  for (int j = 0; j < S; ++j) op[j * 16 + r] = outv[j];
  if (r < S) mp[r] = ((killed >> r) & 1u) ? 0.0f : 1.0f;
}

extern "C" void kernel_launch(void* const* d_in, const int* in_sizes, int n_in,
                              void* d_out, int out_size, void* d_ws, size_t ws_size,
                              hipStream_t stream) {
  const float* slots = (const float*)d_in[0];
  float* out = (float*)d_out;
  const int B = in_sizes[0] / (S * D);          // 131072
  const long long waves  = ((long long)B + 3) / 4;   // 4 batches per wave
  const int blocks = (int)((waves + 3) / 4);         // 4 waves (256 thr) per block
  slot_merge_kernel<<<blocks, 256, 0, stream>>>(slots, out, B);
}